// Round 6
// baseline (120.914 us; speedup 1.0000x reference)
//
#include <hip/hip_runtime.h>

#define B_DIM 256
#define IN_DIM 512
#define OUT_DIM 1024

typedef __attribute__((__ext_vector_type__(2))) float v2f;

// ---------- bit decode: [8] spike bits -> fp32 (exact E4M3 value) ----------
__device__ __forceinline__ float dec_pair(float4 a, float4 b) {
    int ef  = ((int)a.y << 3) | ((int)a.z << 2) | ((int)a.w << 1) | (int)b.x;
    int man = ((int)b.y << 2) | ((int)b.z << 1) | (int)b.w;
    float mag;
    if (ef > 0)
        mag = __uint_as_float(((unsigned)(ef + 120) << 23) | ((unsigned)man << 20));
    else
        mag = (float)man * 0.001953125f;  // man * 2^-9 (subnormal)
    return (a.x != 0.0f) ? -mag : mag;
}

// One dispatch decodes both x (v < 131072) and w (rest). Branch is uniform
// per block (131072 = 512 full blocks).
__global__ void k_decode(const float* __restrict__ xbits,
                         const float* __restrict__ wbits,
                         float* __restrict__ xf, float* __restrict__ wt) {
    int v = blockIdx.x * 256 + threadIdx.x;          // 0 .. 655359
    if (v < B_DIM * IN_DIM) {
        const float4* p = (const float4*)xbits + (size_t)v * 2;
        xf[v] = dec_pair(p[0], p[1]);
    } else {
        int u = v - B_DIM * IN_DIM;
        const float4* p = (const float4*)wbits + (size_t)u * 2;
        float val = dec_pair(p[0], p[1]);
        int o = u >> 9, i = u & 511;
        // wt layout [(i>>2)][o][i&3]: one coalesced dwordx4 per 4 K-steps in k_main
        wt[((size_t)(i >> 2) * OUT_DIM + o) * 4 + (i & 3)] = val;
    }
}

// ---------- encode fp32 (exact E4M3) -> [8] spike bits ----------
__device__ __forceinline__ void store8(float* __restrict__ out, int idx, float v) {
    unsigned au = __float_as_uint(v) & 0x7fffffffu;
    float sgn = (v < 0.0f) ? 1.0f : 0.0f;           // -0.0 -> sign bit 0, like ref
    int ef, man;
    if (au >= 0x3c800000u) {                         // |v| >= 2^-6 : normal
        ef  = (int)(au >> 23) - 120;                 // (exp-127)+7
        man = (int)((au >> 20) & 7u);
    } else {                                         // subnormal / zero
        ef  = 0;
        man = (int)(__uint_as_float(au) * 512.0f);   // exact multiple of 2^-9
    }
    float4 lo = make_float4(sgn,
                            (float)((ef >> 3) & 1), (float)((ef >> 2) & 1),
                            (float)((ef >> 1) & 1));
    float4 hi = make_float4((float)(ef & 1),
                            (float)((man >> 2) & 1), (float)((man >> 1) & 1),
                            (float)(man & 1));
    float4* op = (float4*)(out + (size_t)idx * 8);
    op[0] = lo;
    op[1] = hi;
}

// ---------- full-rate E4M3 RNE quantizer (replaces fp8 cvt pipe) ----------
// Normal range: Veltkamp/Dekker split with C=2^20+1 -> hi = RNE(v to 4 sig
// bits) — exact theorem, ties-to-even inherited from fp32 RNE.
// Subnormal range (|v| < 2^-6): magic-add fixed-point RNE at ulp 2^-9.
// Inputs are always EXACT in fp32 (products <=8 sig bits, sums <=21 bits),
// so this matches the reference quantizer bit-for-bit.
// contract(off): FMA contraction of (p - v) would break the Dekker split.
__device__ __forceinline__ v2f q2(v2f v) {
#pragma clang fp contract(off)
    const v2f C = {1048577.0f, 1048577.0f};          // 2^20 + 1
    const v2f S = {24576.0f, 24576.0f};              // 1.5 * 2^23 * 2^-9
    v2f p  = v * C;
    v2f d  = p - v;
    v2f hi = p - d;
    v2f t  = v + S;
    v2f qs = t - S;
    v2f r;
    r.x = (__builtin_fabsf(v.x) >= 0.015625f) ? hi.x : qs.x;
    r.y = (__builtin_fabsf(v.y) >= 0.015625f) ? hi.y : qs.y;
    return r;
}

// products for one group of 8 k-steps: pf[k] = q(xpair_k * w_k)
__device__ __forceinline__ void products8(v2f* pf, const float4* xc,
                                          float4 cwA, float4 cwB) {
    float wk[8] = {cwA.x, cwA.y, cwA.z, cwA.w, cwB.x, cwB.y, cwB.z, cwB.w};
    const v2f* xp = (const v2f*)xc;                  // 8 packed pairs
#pragma unroll
    for (int k = 0; k < 8; ++k) {
        v2f wv = {wk[k], wk[k]};
        pf[k] = q2(xp[k] * wv);                      // v_pk_mul + 9 full-rate ops
    }
}

// ---------- main sequential-quantized accumulation ----------
// grid (B/8, OUT/64) -- b fastest so co-resident blocks share w in L2.
// block 256 = 4 waves; lane -> o, wave -> 2 b-rows packed into one v2f chain.
// Same pipeline structure as R5 (LDS x interleaved pairs, unconditional w
// depth-4 prefetch, products one group ahead); the q() is now full-rate
// VALU emulation instead of the slow fp8 cvt pipe.
__global__ __launch_bounds__(256) void k_main(const float* __restrict__ xf,
                                              const float* __restrict__ wt,
                                              float* __restrict__ out) {
    __shared__ float xs[8 * IN_DIM + 32];            // +32: tail-overread pad
    int tid  = threadIdx.x;
    int lane = tid & 63;
    int wid  = tid >> 6;
    int o  = blockIdx.y * 64 + lane;
    int b0 = blockIdx.x * 8 + wid * 2;

    // ---- stage this wave's 2 x-rows as interleaved pairs ----
    {
        const float4* ra = (const float4*)(xf + (size_t)b0 * IN_DIM) + lane * 2;
        const float4* rb = (const float4*)(xf + (size_t)(b0 + 1) * IN_DIM) + lane * 2;
        float4 a0 = ra[0], a1 = ra[1];
        float4 c0 = rb[0], c1 = rb[1];
        float4* dst = (float4*)(xs + (size_t)wid * 2 * IN_DIM) + lane * 4;
        dst[0] = make_float4(a0.x, c0.x, a0.y, c0.y);
        dst[1] = make_float4(a0.z, c0.z, a0.w, c0.w);
        dst[2] = make_float4(a1.x, c1.x, a1.y, c1.y);
        dst[3] = make_float4(a1.z, c1.z, a1.w, c1.w);
    }
    __syncthreads();

    const float4* xls = (const float4*)(xs + (size_t)wid * 2 * IN_DIM);  // 256 f4
    const float4* wq  = (const float4*)wt + o;       // stride OUT_DIM f4 per i4

    v2f acc = {0.0f, 0.0f};                          // q(0 + p0) == p0: safe init

    // w slots hold groups 0..3
    float4 wA[4], wB[4];
#pragma unroll
    for (int d = 0; d < 4; ++d) {
        wA[d] = wq[(size_t)(2 * d) * OUT_DIM];
        wB[d] = wq[(size_t)(2 * d + 1) * OUT_DIM];
    }
    // x for group 0, then products(0), then x for group 1
    float4 xc0 = xls[0], xc1 = xls[1], xc2 = xls[2], xc3 = xls[3];
    v2f pf[8];
    {
        float4 xc[4] = {xc0, xc1, xc2, xc3};
        products8(pf, xc, wA[0], wB[0]);
    }
    xc0 = xls[4]; xc1 = xls[5]; xc2 = xls[6]; xc3 = xls[7];

    for (int go = 0; go < 64; go += 4) {
#pragma unroll
        for (int ph = 0; ph < 4; ++ph) {
            int g = go + ph;
            // products for group g+1 (xc holds g+1; w slot (ph+1)&3 holds g+1;
            // at g=63 this consumes garbage into a dead pf_next — harmless)
            v2f pf_next[8];
            {
                float4 xc[4] = {xc0, xc1, xc2, xc3};
                products8(pf_next, xc, wA[(ph + 1) & 3], wB[(ph + 1) & 3]);
            }
            // unconditional prefetches: w group g+4 into slot ph, x group g+2
            wA[ph] = wq[(size_t)(2 * (g + 4)) * OUT_DIM];
            wB[ph] = wq[(size_t)(2 * (g + 4) + 1) * OUT_DIM];
            {
                const float4* xn = xls + 4 * (g + 2);
                xc0 = xn[0]; xc1 = xn[1]; xc2 = xn[2]; xc3 = xn[3];
            }
            // serial acc phase for group g: acc = q(acc + pf[k])
#pragma unroll
            for (int k = 0; k < 8; ++k)
                acc = q2(acc + pf[k]);               // pk_add + 9 full-rate ops
#pragma unroll
            for (int k = 0; k < 8; ++k) pf[k] = pf_next[k];
        }
    }

    store8(out, b0 * OUT_DIM + o, acc.x);
    store8(out, (b0 + 1) * OUT_DIM + o, acc.y);
}

extern "C" void kernel_launch(void* const* d_in, const int* in_sizes, int n_in,
                              void* d_out, int out_size, void* d_ws, size_t ws_size,
                              hipStream_t stream) {
    const float* xb = (const float*)d_in[0];   // [256][512][8]
    const float* wb = (const float*)d_in[1];   // [1024][512][8]
    float* out = (float*)d_out;                // [256][1024][8]

    float* xf = (float*)d_ws;                        // 131072 floats
    float* wt = (float*)d_ws + B_DIM * IN_DIM;       // 524288 floats
    // (w prefetch tail reads up to ~128 KB past wt end — ws is ~268 MB)

    int total = B_DIM * IN_DIM + OUT_DIM * IN_DIM;   // 655360
    k_decode<<<dim3(total / 256), dim3(256), 0, stream>>>(xb, wb, xf, wt);

    dim3 grid(B_DIM / 8, OUT_DIM / 64);
    k_main<<<grid, dim3(256), 0, stream>>>(xf, wt, out);
}

// Round 7
// 101.391 us; speedup vs baseline: 1.1925x; 1.1925x over previous
//
#include <hip/hip_runtime.h>

#define B_DIM 256
#define IN_DIM 512
#define OUT_DIM 1024

typedef __attribute__((__ext_vector_type__(2))) float v2f;

// ---------- bit decode: [8] spike bits -> fp32 (exact E4M3 value) ----------
__device__ __forceinline__ float dec_pair(float4 a, float4 b) {
    int ef  = ((int)a.y << 3) | ((int)a.z << 2) | ((int)a.w << 1) | (int)b.x;
    int man = ((int)b.y << 2) | ((int)b.z << 1) | (int)b.w;
    float mag;
    if (ef > 0)
        mag = __uint_as_float(((unsigned)(ef + 120) << 23) | ((unsigned)man << 20));
    else
        mag = (float)man * 0.001953125f;  // man * 2^-9 (subnormal)
    return (a.x != 0.0f) ? -mag : mag;
}

// One dispatch decodes both x (v < 131072) and w (rest). Branch is uniform
// per block (131072 = 512 full blocks).
__global__ void k_decode(const float* __restrict__ xbits,
                         const float* __restrict__ wbits,
                         float* __restrict__ xf, float* __restrict__ wt) {
    int v = blockIdx.x * 256 + threadIdx.x;          // 0 .. 655359
    if (v < B_DIM * IN_DIM) {
        const float4* p = (const float4*)xbits + (size_t)v * 2;
        xf[v] = dec_pair(p[0], p[1]);
    } else {
        int u = v - B_DIM * IN_DIM;
        const float4* p = (const float4*)wbits + (size_t)u * 2;
        float val = dec_pair(p[0], p[1]);
        int o = u >> 9, i = u & 511;
        // wt layout [(i>>2)][o][i&3]: one coalesced dwordx4 per 4 K-steps in k_main
        wt[((size_t)(i >> 2) * OUT_DIM + o) * 4 + (i & 3)] = val;
    }
}

// ---------- encode fp32 (exact E4M3) -> [8] spike bits ----------
__device__ __forceinline__ void store8(float* __restrict__ out, int idx, float v) {
    unsigned au = __float_as_uint(v) & 0x7fffffffu;
    float sgn = (v < 0.0f) ? 1.0f : 0.0f;           // -0.0 -> sign bit 0, like ref
    int ef, man;
    if (au >= 0x3c800000u) {                         // |v| >= 2^-6 : normal
        ef  = (int)(au >> 23) - 120;                 // (exp-127)+7
        man = (int)((au >> 20) & 7u);
    } else {                                         // subnormal / zero
        ef  = 0;
        man = (int)(__uint_as_float(au) * 512.0f);   // exact multiple of 2^-9
    }
    float4 lo = make_float4(sgn,
                            (float)((ef >> 3) & 1), (float)((ef >> 2) & 1),
                            (float)((ef >> 1) & 1));
    float4 hi = make_float4((float)(ef & 1),
                            (float)((man >> 2) & 1), (float)((man >> 1) & 1),
                            (float)(man & 1));
    float4* op = (float4*)(out + (size_t)idx * 8);
    op[0] = lo;
    op[1] = hi;
}

// ---------- serial-chain quantizer: pure 3-op Dekker ----------
// Valid ONLY for v = sum of two E4M3 values: such v is a multiple of 2^-9,
// so when |v| < 2^-6 it is already exactly representable (<=3 sig bits) and
// 4-sig-bit RNE leaves it unchanged; when |v| >= 2^-6, E4M3 RNE == round to
// 4 significant bits == Veltkamp/Dekker split with C = 2^20+1 (RNE & binade
// crossing inherited from fp32). No subnormal select, no clamp (|acc| << 448
// on this data — proven bit-exact in R2-R6 without clamps).
__device__ __forceinline__ v2f dek2(v2f v) {
#pragma clang fp contract(off)
    const v2f C = {1048577.0f, 1048577.0f};          // 2^20 + 1
    v2f p = v * C;                                   // v_pk_mul_f32
    v2f d = p - v;                                   // v_pk_add_f32 (neg)
    return p - d;                                    // v_pk_add_f32 (neg)
}

// ---------- main sequential-quantized accumulation ----------
// grid (B/8, OUT/64) -- b fastest so co-resident blocks share w in L2.
// block 256 = 4 waves; lane -> o, wave -> 2 b-rows packed into one v2f chain.
// x: one-time LDS stage (interleaved pairs) + 1-group register prefetch.
// w: depth-4 unconditional register prefetch, pointer-increment addressing.
// Inner loop interleaves product(g+1,k) (cvt-based q, independent, pipelines)
// with serial step(g,k) (full-rate Dekker chain) 1:1.
__global__ __launch_bounds__(256) void k_main(const float* __restrict__ xf,
                                              const float* __restrict__ wt,
                                              float* __restrict__ out) {
    __shared__ float xs[8 * IN_DIM + 32];            // +32: tail-overread pad
    int tid  = threadIdx.x;
    int lane = tid & 63;
    int wid  = tid >> 6;
    int o  = blockIdx.y * 64 + lane;
    int b0 = blockIdx.x * 8 + wid * 2;

    // ---- stage this wave's 2 x-rows as interleaved pairs ----
    {
        const float4* ra = (const float4*)(xf + (size_t)b0 * IN_DIM) + lane * 2;
        const float4* rb = (const float4*)(xf + (size_t)(b0 + 1) * IN_DIM) + lane * 2;
        float4 a0 = ra[0], a1 = ra[1];
        float4 c0 = rb[0], c1 = rb[1];
        float4* dst = (float4*)(xs + (size_t)wid * 2 * IN_DIM) + lane * 4;
        dst[0] = make_float4(a0.x, c0.x, a0.y, c0.y);
        dst[1] = make_float4(a0.z, c0.z, a0.w, c0.w);
        dst[2] = make_float4(a1.x, c1.x, a1.y, c1.y);
        dst[3] = make_float4(a1.z, c1.z, a1.w, c1.w);
    }
    __syncthreads();

    const float4* xls = (const float4*)(xs + (size_t)wid * 2 * IN_DIM);  // 256 f4
    const float4* wq  = (const float4*)wt + o;       // stride OUT_DIM f4 per i4

    v2f acc = {0.0f, 0.0f};                          // q(0 + p0) == p0: safe init

    // w slots hold groups 0..3 (slot d <- group d)
    float4 wA[4], wB[4];
    {
        const float4* wp = wq;
#pragma unroll
        for (int d = 0; d < 4; ++d) {
            wA[d] = wp[0];
            wB[d] = wp[OUT_DIM];
            wp += 2 * OUT_DIM;
        }
    }
    const float4* wqp = wq + (size_t)8 * OUT_DIM;    // next w prefetch: group 4

    // pf = products(group 0); xc <- group 1
    float4 xc0 = xls[0], xc1 = xls[1], xc2 = xls[2], xc3 = xls[3];
    v2f pf[8];
    {
        float wk[8] = {wA[0].x, wA[0].y, wA[0].z, wA[0].w,
                       wB[0].x, wB[0].y, wB[0].z, wB[0].w};
        float4 xcl[4] = {xc0, xc1, xc2, xc3};
        const v2f* xp = (const v2f*)xcl;
#pragma unroll
        for (int k = 0; k < 8; ++k) {
            v2f wv = {wk[k], wk[k]};
            v2f pr = xp[k] * wv;
            int pq = __builtin_amdgcn_cvt_pk_fp8_f32(pr.x, pr.y, 0, false);
            pf[k] = __builtin_amdgcn_cvt_pk_f32_fp8(pq, false);
        }
    }
    xc0 = xls[4]; xc1 = xls[5]; xc2 = xls[6]; xc3 = xls[7];
    const float4* xlp = xls + 8;                     // next x prefetch: group 2

    for (int go = 0; go < 64; go += 4) {
#pragma unroll
        for (int ph = 0; ph < 4; ++ph) {
            // phase g = go + ph. xc holds group g+1; w slot (ph+1)&3 holds
            // group g+1. Interleave products(g+1) with serial(g) 1:1.
            float4 cwA = wA[(ph + 1) & 3], cwB = wB[(ph + 1) & 3];
            float wk[8] = {cwA.x, cwA.y, cwA.z, cwA.w,
                           cwB.x, cwB.y, cwB.z, cwB.w};
            float4 xcl[4] = {xc0, xc1, xc2, xc3};
            const v2f* xp = (const v2f*)xcl;
            v2f pf_next[8];
#pragma unroll
            for (int k = 0; k < 8; ++k) {
                v2f wv = {wk[k], wk[k]};
                v2f pr = xp[k] * wv;                 // independent: fills chain
                int pq = __builtin_amdgcn_cvt_pk_fp8_f32(pr.x, pr.y, 0, false);
                pf_next[k] = __builtin_amdgcn_cvt_pk_f32_fp8(pq, false);
                acc = dek2(acc + pf[k]);             // full-rate serial chain
            }
            // unconditional prefetches: w group g+4 into slot ph, x group g+2
            wA[ph] = wqp[0];
            wB[ph] = wqp[OUT_DIM];
            wqp += 2 * OUT_DIM;
            xc0 = xlp[0]; xc1 = xlp[1]; xc2 = xlp[2]; xc3 = xlp[3];
            xlp += 4;
#pragma unroll
            for (int k = 0; k < 8; ++k) pf[k] = pf_next[k];
        }
    }

    store8(out, b0 * OUT_DIM + o, acc.x);
    store8(out, (b0 + 1) * OUT_DIM + o, acc.y);
}

extern "C" void kernel_launch(void* const* d_in, const int* in_sizes, int n_in,
                              void* d_out, int out_size, void* d_ws, size_t ws_size,
                              hipStream_t stream) {
    const float* xb = (const float*)d_in[0];   // [256][512][8]
    const float* wb = (const float*)d_in[1];   // [1024][512][8]
    float* out = (float*)d_out;                // [256][1024][8]

    float* xf = (float*)d_ws;                        // 131072 floats
    float* wt = (float*)d_ws + B_DIM * IN_DIM;       // 524288 floats
    // (w prefetch tail reads up to ~256 KB past wt end — ws is ~268 MB)

    int total = B_DIM * IN_DIM + OUT_DIM * IN_DIM;   // 655360
    k_decode<<<dim3(total / 256), dim3(256), 0, stream>>>(xb, wb, xf, wt);

    dim3 grid(B_DIM / 8, OUT_DIM / 64);
    k_main<<<grid, dim3(256), 0, stream>>>(xf, wt, out);
}